// Round 1
// baseline (894.163 us; speedup 1.0000x reference)
//
#include <hip/hip_runtime.h>
#include <math.h>

// Problem constants (from reference): x (128,128,128) f32, W0 (9,9,128,128) f32
#define NB   128        // batch / scan steps
#define NC   81         // 9*9 map cells
#define MH   9
#define HW   16384      // 128*128 feature elems per cell

__device__ __forceinline__ unsigned long long pack_key(float d, unsigned int idx) {
    // d >= 0 -> IEEE bits are order-preserving; low 32 bits = flat index so
    // ties resolve to the smallest index (matches np.argmin first-occurrence).
    return ((unsigned long long)__float_as_uint(d) << 32) | (unsigned long long)idx;
}

__device__ __forceinline__ unsigned long long ullmin(unsigned long long a, unsigned long long b) {
    return a < b ? a : b;
}

// g for one map cell (i,j) given global-flat argmin index and its ring sum.
// Replicates reference f32 op sequence: wx=flat//9, wy=flat%9,
// dist=sqrt((i-wx)^2+(j-wy)^2), gauss=exp(-dist^2/(2 r^2)), g=lr*gauss*rings,
// g = (g<radius)? g : 0
__device__ __forceinline__ float g_update(int i, int j, unsigned int flat, float rings,
                                          float lr, float radius, float denom) {
    unsigned int wx = flat / 9u;
    unsigned int wy = flat % 9u;
    float fdx = (float)(i - (int)wx);
    float fdy = (float)(j - (int)wy);
    float dist = sqrtf(fdx * fdx + fdy * fdy);
    float gauss = expf(-(dist * dist) / denom);
    float g = lr * gauss * rings;
    return (g < radius) ? g : 0.0f;
}

// ---------------- kernel 0: init argmin slots (ws is poisoned 0xAA each call) --
__global__ void k_init(unsigned long long* __restrict__ amin0) {
    if (threadIdx.x < NB) amin0[threadIdx.x] = ~0ull;
}

// ---------------- kernel 1: parallel precompute at off==0 ---------------------
// grid = NC * 16 blocks; block (c, tg) handles cell c for t in [tg*8, tg*8+8).
// W0 cell slice cached in registers (64 f32/thread), x_t streamed from L2/L3.
__global__ __launch_bounds__(256) void k_precompute(const float* __restrict__ x,
                                                    const float* __restrict__ w0,
                                                    float* __restrict__ rings0,
                                                    unsigned long long* __restrict__ amin0) {
    const int c   = blockIdx.x >> 4;   // 0..80
    const int tg  = blockIdx.x & 15;   // 0..15
    const int tid = threadIdx.x;

    const float4* w4 = (const float4*)(w0 + c * HW);
    float4 wreg[16];
#pragma unroll
    for (int k = 0; k < 16; ++k) wreg[k] = w4[tid + (k << 8)];

    __shared__ float sSum[4];
    __shared__ unsigned long long sMin[4];

    for (int tt = 0; tt < 8; ++tt) {
        const int t = tg * 8 + tt;
        const float4* x4 = (const float4*)(x + t * HW);
        float acc = 0.0f;
        unsigned long long best = ~0ull;
#pragma unroll
        for (int k = 0; k < 16; ++k) {
            const int i4 = tid + (k << 8);
            float4 xv = x4[i4];
            float4 wv = wreg[k];
            float d0 = fabsf(wv.x - xv.x);
            float d1 = fabsf(wv.y - xv.y);
            float d2 = fabsf(wv.z - xv.z);
            float d3 = fabsf(wv.w - xv.w);
            acc += d0 + d1 + d2 + d3;
            unsigned int base = (unsigned int)(c * HW + i4 * 4);
            best = ullmin(best, pack_key(d0, base + 0));
            best = ullmin(best, pack_key(d1, base + 1));
            best = ullmin(best, pack_key(d2, base + 2));
            best = ullmin(best, pack_key(d3, base + 3));
        }
        // wave(64) reduce
#pragma unroll
        for (int s = 32; s; s >>= 1) {
            acc += __shfl_down(acc, s);
            unsigned long long o = __shfl_down(best, s);
            best = ullmin(best, o);
        }
        const int wave = tid >> 6, lane = tid & 63;
        if (lane == 0) { sSum[wave] = acc; sMin[wave] = best; }
        __syncthreads();
        if (tid == 0) {
            rings0[t * NC + c] = sSum[0] + sSum[1] + sSum[2] + sSum[3];
            unsigned long long m = ullmin(ullmin(sMin[0], sMin[1]), ullmin(sMin[2], sMin[3]));
            atomicMin(&amin0[t], m);
        }
        __syncthreads();   // protect sSum/sMin reuse next t
    }
}

// ---------------- kernel 2: sequential scan (1 block) -------------------------
// Fast path (off==0, the overwhelmingly likely case): wave 0 consumes the
// precomputed rings0/amin0 from LDS; per-lane register state. If off ever goes
// nonzero, fall to an exact slow path that recomputes rings/argmin with the
// current offsets (single block; correct, rarely/never executed).
__global__ __launch_bounds__(256) void k_scan(const float* __restrict__ x,
                                              const float* __restrict__ w0,
                                              const float* __restrict__ rings0,
                                              const unsigned long long* __restrict__ amin0,
                                              float* __restrict__ off_out) {
    __shared__ float sR0[NB * NC];            // 41472 B
    __shared__ unsigned long long sA0[NB];    // 1024 B
    __shared__ float sOff[NC];
    __shared__ float sRings[NC];
    __shared__ unsigned long long sAmin;
    __shared__ int sDirtyT;

    const int tid = threadIdx.x;
    const float lr     = (float)0.9900498337491681;   // 1.0*exp(-0.01) -> f32
    const float radius = (float)4.9502491687458405;   // 5.0*exp(-0.01) -> f32
    const float denom  = 2.0f * (radius * radius);

    for (int i = tid; i < NB * NC; i += 256) sR0[i] = rings0[i];
    for (int i = tid; i < NB; i += 256) sA0[i] = amin0[i];
    if (tid < NC) sOff[tid] = 0.0f;
    if (tid == 0) sDirtyT = NB;
    __syncthreads();

    if (tid < 64) {
        // lane handles cell c0 = tid and (if <81) c1 = tid+64
        const int c0 = tid, c1 = tid + 64;
        const int i0 = c0 / MH, j0 = c0 % MH;
        const int i1 = c1 / MH, j1 = c1 % MH;
        float off0 = 0.0f, off1 = 0.0f;
        for (int t = 0; t < NB; ++t) {
            const unsigned int flat = (unsigned int)sA0[t];
            float g0 = g_update(i0, j0, flat, sR0[t * NC + c0], lr, radius, denom);
            float g1 = (c1 < NC) ? g_update(i1, j1, flat, sR0[t * NC + c1], lr, radius, denom)
                                 : 0.0f;
            off0 += g0; off1 += g1;
            off_out[t * NC + c0] = off0;
            if (c1 < NC) off_out[t * NC + c1] = off1;
            if (__any((g0 != 0.0f) || (g1 != 0.0f))) {
                // offsets went nonzero: precomputed values invalid from t+1 on
                sOff[c0] = off0;
                if (c1 < NC) sOff[c1] = off1;
                if (tid == 0) sDirtyT = t + 1;
                break;
            }
        }
    }
    __syncthreads();

    const int t0 = sDirtyT;
    for (int t = t0; t < NB; ++t) {                 // exact fallback (rare)
        if (tid < NC) sRings[tid] = 0.0f;
        if (tid == 0) sAmin = ~0ull;
        __syncthreads();
        unsigned long long best = ~0ull;
        const float* xt = x + t * HW;
        for (int c = 0; c < NC; ++c) {
            const float o = sOff[c];
            const float* wc = w0 + c * HW;
            float acc = 0.0f;
            for (int k = 0; k < 64; ++k) {
                const int p = tid + (k << 8);
                const float d = fabsf((wc[p] + o) - xt[p]);
                acc += d;
                best = ullmin(best, pack_key(d, (unsigned int)(c * HW + p)));
            }
#pragma unroll
            for (int s = 32; s; s >>= 1) acc += __shfl_down(acc, s);
            if ((tid & 63) == 0) atomicAdd(&sRings[c], acc);
        }
#pragma unroll
        for (int s = 32; s; s >>= 1) {
            unsigned long long o2 = __shfl_down(best, s);
            best = ullmin(best, o2);
        }
        if ((tid & 63) == 0) atomicMin(&sAmin, best);
        __syncthreads();
        if (tid < NC) {
            const unsigned int flat = (unsigned int)sAmin;
            const float g = g_update(tid / MH, tid % MH, flat, sRings[tid], lr, radius, denom);
            const float no = sOff[tid] + g;
            sOff[tid] = no;
            off_out[t * NC + tid] = no;
        }
        __syncthreads();
    }
}

// ---------------- kernel 3: broadcast output out[t,c,:] = W0[c,:] + off[t,c] --
__global__ __launch_bounds__(256) void k_out(const float* __restrict__ w0,
                                             const float* __restrict__ off_out,
                                             float* __restrict__ out) {
    const int bc  = blockIdx.x;          // t*81 + c
    const int c   = bc % NC;
    const int tid = threadIdx.x;
    const float o = off_out[bc];
    const float4* w4 = (const float4*)(w0 + c * HW);
    float4* o4 = (float4*)(out + (size_t)bc * HW);
#pragma unroll
    for (int k = 0; k < 16; ++k) {
        float4 v = w4[tid + (k << 8)];
        v.x += o; v.y += o; v.z += o; v.w += o;
        o4[tid + (k << 8)] = v;
    }
}

extern "C" void kernel_launch(void* const* d_in, const int* in_sizes, int n_in,
                              void* d_out, int out_size, void* d_ws, size_t ws_size,
                              hipStream_t stream) {
    const float* x  = (const float*)d_in[0];   // (128,128,128)
    const float* w0 = (const float*)d_in[1];   // (9,9,128,128)
    float* out = (float*)d_out;                // (128,9,9,128,128)

    // workspace layout (~84 KB): off_out | rings0 | amin0
    float* off_out = (float*)d_ws;                          // NB*NC f32
    float* rings0  = off_out + NB * NC;                     // NB*NC f32
    unsigned long long* amin0 = (unsigned long long*)(rings0 + NB * NC); // NB u64

    k_init<<<1, 128, 0, stream>>>(amin0);
    k_precompute<<<NC * 16, 256, 0, stream>>>(x, w0, rings0, amin0);
    k_scan<<<1, 256, 0, stream>>>(x, w0, rings0, amin0, off_out);
    k_out<<<NB * NC, 256, 0, stream>>>(w0, off_out, out);
}